// Round 5
// baseline (732.591 us; speedup 1.0000x reference)
//
#include <hip/hip_runtime.h>
#include <hip/hip_bf16.h>

#define BB 256
#define NN 257
#define NT 256   // tokens per batch (N-1)
#define DD 768
#define KC 8     // K clusters
#define VV 10000
#define ITERS 4

#define CHD 32               // sim: dims per staged chunk (128 B / token)
#define NCH (DD / CHD)       // 24 chunks per sim sweep
#define CF4 (CHD / 4)        // 8 float4 per token per chunk
#define CSTR 193             // cent row stride in float4 (772 dwords)

__device__ __forceinline__ float waveReduceSum(float v) {
#pragma unroll
    for (int off = 32; off > 0; off >>= 1)
        v += __shfl_xor(v, off, 64);
    return v;
}

__device__ __forceinline__ float dot4chain(float4 a, float4 c, float acc) {
    // exact chain from all passing rounds (x,y,z,w ascending)
    return fmaf(a.w, c.w, fmaf(a.z, c.z, fmaf(a.y, c.y, fmaf(a.x, c.x, acc))));
}

// Async global->LDS DMA, 16 B per lane, LDS dest = wave-uniform base + lane*16.
__device__ __forceinline__ void gld16(const float* g, void* lds) {
    __builtin_amdgcn_global_load_lds(
        (const __attribute__((address_space(1))) void*)g,
        (__attribute__((address_space(3))) void*)lds,
        16, 0, 0);
}

// One block (1024 threads, 16 waves) per batch.
//
// R5: sim loop is BARRIER-FREE. Sim thread mapping changed from
// t=g*256+tok to t=tok*4+g, so wave v consumes exactly tokens
// [16v,16v+16) -- precisely the tokens wave v itself DMA-stages
// (slot=v*128+lane => token=slot>>3 in [16v,16v+16)). Consumption
// depends only on the wave's OWN global_load_lds completions, tracked by
// its OWN s_waitcnt vmcnt (per-wave FIFO counter) -> the 24 per-chunk
// block barriers are gone; waves drift and self-pipeline. The old
// structure paid max-of-16-waves DMA jitter at every chunk barrier
// (96 barriers/dispatch) -- the R4 experiment showed sync structure,
// not VALU or bytes, moves wall time.
//
// Accumulate reverted to the R3 direct-global-load form (R4's
// producer-consumer LDS staging regressed 420->461: 32 extra barriers +
// an LDS round-trip for once-consumed data).
//
// maskF is its own 8 KB array (no tbuf overlay) -> mask writes never
// alias staging buffers; one __syncthreads per iter makes masks visible.
// LDS: cent 48.25K + tbuf 96K + mask 8K = 152.3 KB, 1 block/CU.
//
// Bit-exactness: every (tok,row) sim dot chain, mask compare, accumulate
// n-ascending fmaf chain, c0 = tsum-c1 subtraction, and norm reduce is
// the identical fp op sequence as the passing R3 kernel -- only the
// thread IDs owning them changed. Bank check: tb reads are 4-lane
// broadcast groups spread by ^(tok&7) over 8 quads = 2-way (free);
// cr reads are 4 addrs/wave at quads {j4, j4+4} = 2-way (free).
__global__ __launch_bounds__(1024, 4) void kmeans_kernel(
    const float* __restrict__ tokens,
    const float* __restrict__ vc,
    const int* __restrict__ topk,
    float* __restrict__ out_assign,   // (B, 256, 8) float
    float* __restrict__ delta)        // (V) float accumulators (pre-zeroed)
{
    __shared__ float4 cent4[16 * CSTR];       // 49408 B normalized centroids (row = 2k+c)
    __shared__ float4 tbuf4[3 * 2048];        // 96 KB triple-buffered swizzled chunks
    __shared__ float4 maskF4[NT * 2];         // 8 KB  [NT][8] float masks
    __shared__ int sidx[KC];

    float* centf  = (float*)cent4;
    float* maskFf = (float*)maskF4;

    const int b = blockIdx.x;
    const int t = threadIdx.x;
    const int lane = t & 63;
    const int wave = t >> 6;

    if (t < KC) sidx[t] = topk[b * KC + t];
    __syncthreads();

    // ---- gather + L2-normalize 16 initial centroid rows: wave r -> row r
    {
        const int r = wave;
        const int k = r >> 1, c = r & 1;
        const float* src = vc + ((size_t)sidx[k] * 2 + c) * DD;
        float vals[12];
        float ss = 0.f;
#pragma unroll
        for (int j = 0; j < 12; ++j) {
            vals[j] = src[lane + 64 * j];
            ss = fmaf(vals[j], vals[j], ss);
        }
        ss = waveReduceSum(ss);
        float iv = 1.0f / fmaxf(sqrtf(ss), 1e-12f);
#pragma unroll
        for (int j = 0; j < 12; ++j)
            centf[r * 772 + lane + 64 * j] = vals[j] * iv;
    }
    __syncthreads();

    const float* tpb = tokens + ((size_t)b * NN + 1) * DD;

    // sim roles (R5): thread = tok*4 + g  -> wave v owns tokens [16v,16v+16)
    const int tok = t >> 2;
    const int g   = t & 3;
    const int s7  = tok & 7;

    // DMA lane roles: wave stages its OWN tokens' chunk slots [wave*128, +128)
    // slot -> token slot>>3, physical f4 q = slot&7, global col = q ^ (tok&7)
    const int slotA = wave * 128 + lane;         // load 0
    const int slotB = slotA + 64;                // load 1
    const float* gbaseA = tpb + (size_t)(slotA >> 3) * DD + 4 * ((slotA & 7) ^ ((slotA >> 3) & 7));
    const float* gbaseB = tpb + (size_t)(slotB >> 3) * DD + 4 * ((slotB & 7) ^ ((slotB >> 3) & 7));

    float tsum_reg = 0.f;   // per-dim token sum, computed it=0, reused it=1..3

    for (int it = 0; it < ITERS; ++it) {
        float acc[4] = {0.f, 0.f, 0.f, 0.f};

        // ============ SIM SWEEP: per-wave self-synchronized, no barriers ======
        // prologue: DMA chunks 0,1 into buffers 0,1 (this wave's region only)
        gld16(gbaseA,       (void*)(tbuf4 + wave * 128));
        gld16(gbaseB,       (void*)(tbuf4 + wave * 128 + 64));
        gld16(gbaseA + CHD, (void*)(tbuf4 + 2048 + wave * 128));
        gld16(gbaseB + CHD, (void*)(tbuf4 + 2048 + wave * 128 + 64));

#pragma unroll 1
        for (int cix = 0; cix < NCH; ++cix) {
            // this wave's chunk cix complete once <=2 of its vm ops remain (FIFO)
            if (cix < NCH - 1) asm volatile("s_waitcnt vmcnt(2)" ::: "memory");
            else               asm volatile("s_waitcnt vmcnt(0)" ::: "memory");
            __builtin_amdgcn_sched_barrier(0);
            if (cix + 2 < NCH) {
                const int nb = (cix + 2) % 3;   // this wave's own region of that
                                                // buffer was consumed at cix-1
                gld16(gbaseA + (cix + 2) * CHD, (void*)(tbuf4 + nb * 2048 + wave * 128));
                gld16(gbaseB + (cix + 2) * CHD, (void*)(tbuf4 + nb * 2048 + wave * 128 + 64));
            }
            // ---- consume chunk cix: advance the 4 row chains over 32 dims
            {
                const float4* tb = tbuf4 + (cix % 3) * 2048 + (tok << 3);
                const float4* cr = cent4 + (g * 4) * CSTR + (cix << 3);
#pragma unroll
                for (int j4 = 0; j4 < CF4; ++j4) {
                    float4 a  = tb[j4 ^ s7];            // own-wave staged, 2-way max
                    float4 c0 = cr[j4];                 // 16-lane broadcast groups
                    float4 c1 = cr[CSTR + j4];
                    float4 c2 = cr[2 * CSTR + j4];
                    float4 c3 = cr[3 * CSTR + j4];
                    acc[0] = dot4chain(a, c0, acc[0]);
                    acc[1] = dot4chain(a, c1, acc[1]);
                    acc[2] = dot4chain(a, c2, acc[2]);
                    acc[3] = dot4chain(a, c3, acc[3]);
                }
            }
        }

        // ---- masks: thread (tok,g) writes float {0,1} for clusters (2g, 2g+1)
        // maskF is a dedicated array -> no aliasing with staging; write now,
        // one barrier makes all masks visible.
        {
            float2 mf;
            mf.x = (acc[1] > acc[0]) ? 1.f : 0.f;    // cluster 2g   (ties -> 0)
            mf.y = (acc[3] > acc[2]) ? 1.f : 0.f;    // cluster 2g+1
            *(float2*)(maskFf + tok * KC + 2 * g) = mf;
        }
        __syncthreads();   // masks visible to all; all waves past sim sweep

        if (it == ITERS - 1 && t < NT) {
            float4* op = (float4*)(out_assign + ((size_t)b * NT + t) * KC);
            op[0] = maskF4[2 * t]; op[1] = maskF4[2 * t + 1];
        }

        // ==== accumulate (R3 form): thread t<768 owns dim d=t, all 8 clusters;
        // ==== writes BOTH unnormalized centroid rows (c1 = a_k, c0 = tsum - a_k)
        if (t < DD) {
            const int d = t;
            const float* col = tpb + d;
            float a0 = 0.f, a1 = 0.f, a2 = 0.f, a3 = 0.f;
            float a4 = 0.f, a5 = 0.f, a6 = 0.f, a7 = 0.f;
            float tr = 0.f;
            for (int n0 = 0; n0 < NT; n0 += 16) {
                float v[16];
#pragma unroll
                for (int u = 0; u < 16; ++u)
                    v[u] = col[(size_t)(n0 + u) * DD];          // coalesced 256B/wave
#pragma unroll
                for (int u = 0; u < 16; ++u) {
                    float4 ma = maskF4[2 * (n0 + u)];           // wave-uniform broadcast
                    float4 mb = maskF4[2 * (n0 + u) + 1];
                    a0 = fmaf(v[u], ma.x, a0);
                    a1 = fmaf(v[u], ma.y, a1);
                    a2 = fmaf(v[u], ma.z, a2);
                    a3 = fmaf(v[u], ma.w, a3);
                    a4 = fmaf(v[u], mb.x, a4);
                    a5 = fmaf(v[u], mb.y, a5);
                    a6 = fmaf(v[u], mb.z, a6);
                    a7 = fmaf(v[u], mb.w, a7);
                    if (it == 0) tr += v[u];                    // n-ascending chain
                }
            }
            if (it == 0) tsum_reg = tr;
            // rows r=2k+1 get a_k; rows r=2k get tsum-a_k (same subtraction the
            // normalize path originally performed -> identical values)
            centf[ 1 * 772 + d] = a0;  centf[ 0 * 772 + d] = tsum_reg - a0;
            centf[ 3 * 772 + d] = a1;  centf[ 2 * 772 + d] = tsum_reg - a1;
            centf[ 5 * 772 + d] = a2;  centf[ 4 * 772 + d] = tsum_reg - a2;
            centf[ 7 * 772 + d] = a3;  centf[ 6 * 772 + d] = tsum_reg - a3;
            centf[ 9 * 772 + d] = a4;  centf[ 8 * 772 + d] = tsum_reg - a4;
            centf[11 * 772 + d] = a5;  centf[10 * 772 + d] = tsum_reg - a5;
            centf[13 * 772 + d] = a6;  centf[12 * 772 + d] = tsum_reg - a6;
            centf[15 * 772 + d] = a7;  centf[14 * 772 + d] = tsum_reg - a7;
        }
        __syncthreads();

        // ==== normalize in place: wave r reads its centf row, reduces, scales
        {
            const int r = wave;
            float vals[12];
            float ss = 0.f;
#pragma unroll
            for (int j = 0; j < 12; ++j) {
                vals[j] = centf[r * 772 + lane + 64 * j];
                ss = fmaf(vals[j], vals[j], ss);
            }
            ss = waveReduceSum(ss);
            float iv = 1.0f / fmaxf(sqrtf(ss), 1e-12f);
#pragma unroll
            for (int j = 0; j < 12; ++j)
                centf[r * 772 + lane + 64 * j] = vals[j] * iv;
        }
        __syncthreads();   // cent ready; tbuf free for next iter's staging
    }

    // ---- scatter: vc[idx,0,0] += centroids_final[b,k,0,0] (c0 row, element 0)
    if (t < KC) {
        atomicAdd(delta + sidx[t], centf[(2 * t) * 772]);
    }
}

__global__ __launch_bounds__(1024) void vcnorm_kernel(
    const float* __restrict__ vc,
    const float* __restrict__ delta,
    float* __restrict__ out)          // (V, 2, D)
{
    const int t = threadIdx.x;
    const int lane = t & 63;
    const int wave = t >> 6;
    const int r = blockIdx.x * 16 + wave;     // row in [0, 2V)
    if (r >= 2 * VV) return;
    const int v = r >> 1;
    const int c = r & 1;
    const float* src = vc + (size_t)r * DD;
    float4 x[3];
#pragma unroll
    for (int j = 0; j < 3; ++j)
        x[j] = *(const float4*)(src + (lane + 64 * j) * 4);
    if (c == 0 && lane == 0) x[0].x += delta[v];
    float ss = 0.f;
#pragma unroll
    for (int j = 0; j < 3; ++j)
        ss += x[j].x * x[j].x + x[j].y * x[j].y + x[j].z * x[j].z + x[j].w * x[j].w;
    ss = waveReduceSum(ss);
    float iv = 1.0f / fmaxf(sqrtf(ss), 1e-12f);
    float* dst = out + (size_t)r * DD;
#pragma unroll
    for (int j = 0; j < 3; ++j) {
        float4 y = make_float4(x[j].x * iv, x[j].y * iv, x[j].z * iv, x[j].w * iv);
        *(float4*)(dst + (lane + 64 * j) * 4) = y;
    }
}

extern "C" void kernel_launch(void* const* d_in, const int* in_sizes, int n_in,
                              void* d_out, int out_size, void* d_ws, size_t ws_size,
                              hipStream_t stream) {
    const float* tokens = (const float*)d_in[0];
    const float* vc     = (const float*)d_in[1];
    const int*   topk   = (const int*)d_in[2];
    float* out          = (float*)d_out;
    float* assignments  = out;                                   // B*NT*KC floats
    float* vcnew        = out + (size_t)BB * NT * KC;            // V*2*D floats
    float* delta        = (float*)d_ws;                          // V floats

    hipMemsetAsync(delta, 0, VV * sizeof(float), stream);
    hipLaunchKernelGGL(kmeans_kernel, dim3(BB), dim3(1024), 0, stream,
                       tokens, vc, topk, assignments, delta);
    hipLaunchKernelGGL(vcnorm_kernel, dim3((2 * VV + 15) / 16), dim3(1024), 0, stream,
                       vc, delta, vcnew);
}

// Round 6
// 635.133 us; speedup vs baseline: 1.1534x; 1.1534x over previous
//
#include <hip/hip_runtime.h>
#include <hip/hip_bf16.h>

#define BB 256
#define NN 257
#define NT 256   // tokens per batch (N-1)
#define DD 768
#define KC 8     // K clusters
#define VV 10000
#define ITERS 4

#define CHD 32               // sim: dims per staged chunk (128 B / token)
#define NCH (DD / CHD)       // 24 chunks per sim sweep
#define CF4 (CHD / 4)        // 8 float4 per token per chunk
#define CSTR 193             // cent row stride in float4 (772 dwords)

__device__ __forceinline__ float waveReduceSum(float v) {
#pragma unroll
    for (int off = 32; off > 0; off >>= 1)
        v += __shfl_xor(v, off, 64);
    return v;
}

__device__ __forceinline__ float dot4chain(float4 a, float4 c, float acc) {
    // exact chain from all passing rounds (x,y,z,w ascending)
    return fmaf(a.w, c.w, fmaf(a.z, c.z, fmaf(a.y, c.y, fmaf(a.x, c.x, acc))));
}

// Async global->LDS DMA, 16 B per lane, LDS dest = wave-uniform base + lane*16.
__device__ __forceinline__ void gld16(const float* g, void* lds) {
    __builtin_amdgcn_global_load_lds(
        (const __attribute__((address_space(1))) void*)g,
        (__attribute__((address_space(3))) void*)lds,
        16, 0, 0);
}

// One block (1024 threads, 16 waves) per batch.
//
// R6: barrier-free sim WITHOUT R5's bank-conflict confound.
// R5 post-mortem: t=tok*4+g put g varying inside each 8-lane LDS phase
// group -> the 4 cr centroid reads went from wave-uniform broadcast to
// multi-address-per-phase -> SQ_LDS_BANK_CONFLICT 1.28e7 -> 9.1e7, 420
// -> 506us. Fix: lane l of wave v -> tok = 16v + (l&15), g = l>>4.
//  (a) wave v consumes exactly tokens [16v,16v+16) = its OWN DMA-staged
//      slots (slot=wave*128+lane => tok=slot>>3) -> per-wave
//      s_waitcnt vmcnt self-sync, ZERO sim barriers, tbuf regions fully
//      wave-private (no cross-wave hazard even across iterations).
//  (b) any aligned 8-lane phase group has UNIFORM g (l>>4 constant) ->
//      cr reads are phase-broadcast, conflict-free exactly like R3.
//  (c) tb reads per phase: 8 consecutive tokens, quad j4^(tok&7) -> 8
//      distinct quads, conflict-free exactly like R3.
// Accumulate (R3 direct-global form), normalize, mask compare, DMA
// pattern, and every fp chain are identical to the passing R3 kernel --
// only lane ownership changed. Bit-exact by construction.
//
// LDS: cent 48.25K + tbuf 96K + mask 8K = 152.3 KB, 1 block/CU, 16 waves.
__global__ __launch_bounds__(1024, 4) void kmeans_kernel(
    const float* __restrict__ tokens,
    const float* __restrict__ vc,
    const int* __restrict__ topk,
    float* __restrict__ out_assign,   // (B, 256, 8) float
    float* __restrict__ delta)        // (V) float accumulators (pre-zeroed)
{
    __shared__ float4 cent4[16 * CSTR];       // 49408 B normalized centroids (row = 2k+c)
    __shared__ float4 tbuf4[3 * 2048];        // 96 KB triple-buffered swizzled chunks
    __shared__ float4 maskF4[NT * 2];         // 8 KB  [NT][8] float masks
    __shared__ int sidx[KC];

    float* centf  = (float*)cent4;
    float* maskFf = (float*)maskF4;

    const int b = blockIdx.x;
    const int t = threadIdx.x;
    const int lane = t & 63;
    const int wave = t >> 6;

    if (t < KC) sidx[t] = topk[b * KC + t];
    __syncthreads();

    // ---- gather + L2-normalize 16 initial centroid rows: wave r -> row r
    {
        const int r = wave;
        const int k = r >> 1, c = r & 1;
        const float* src = vc + ((size_t)sidx[k] * 2 + c) * DD;
        float vals[12];
        float ss = 0.f;
#pragma unroll
        for (int j = 0; j < 12; ++j) {
            vals[j] = src[lane + 64 * j];
            ss = fmaf(vals[j], vals[j], ss);
        }
        ss = waveReduceSum(ss);
        float iv = 1.0f / fmaxf(sqrtf(ss), 1e-12f);
#pragma unroll
        for (int j = 0; j < 12; ++j)
            centf[r * 772 + lane + 64 * j] = vals[j] * iv;
    }
    __syncthreads();

    const float* tpb = tokens + ((size_t)b * NN + 1) * DD;

    // sim roles (R6): lane l of wave v -> tok = 16v+(l&15), g = l>>4.
    // Wave-private tokens; g uniform within every 8-lane phase group.
    const int tok = 16 * wave + (lane & 15);
    const int g   = lane >> 4;
    const int s7  = tok & 7;

    // DMA lane roles: wave stages its OWN tokens' chunk slots [wave*128, +128)
    // slot -> token slot>>3, physical f4 q = slot&7, global col = q ^ (tok&7)
    const int slotA = wave * 128 + lane;         // load 0
    const int slotB = slotA + 64;                // load 1
    const float* gbaseA = tpb + (size_t)(slotA >> 3) * DD + 4 * ((slotA & 7) ^ ((slotA >> 3) & 7));
    const float* gbaseB = tpb + (size_t)(slotB >> 3) * DD + 4 * ((slotB & 7) ^ ((slotB >> 3) & 7));

    float tsum_reg = 0.f;   // per-dim token sum, computed it=0, reused it=1..3

    for (int it = 0; it < ITERS; ++it) {
        float acc[4] = {0.f, 0.f, 0.f, 0.f};

        // ============ SIM SWEEP: per-wave self-synchronized, no barriers ======
        // prologue: DMA chunks 0,1 into buffers 0,1 (this wave's region only)
        gld16(gbaseA,       (void*)(tbuf4 + wave * 128));
        gld16(gbaseB,       (void*)(tbuf4 + wave * 128 + 64));
        gld16(gbaseA + CHD, (void*)(tbuf4 + 2048 + wave * 128));
        gld16(gbaseB + CHD, (void*)(tbuf4 + 2048 + wave * 128 + 64));

#pragma unroll 1
        for (int cix = 0; cix < NCH; ++cix) {
            // this wave's chunk cix complete once <=2 of its vm ops remain (FIFO)
            if (cix < NCH - 1) asm volatile("s_waitcnt vmcnt(2)" ::: "memory");
            else               asm volatile("s_waitcnt vmcnt(0)" ::: "memory");
            __builtin_amdgcn_sched_barrier(0);
            if (cix + 2 < NCH) {
                const int nb = (cix + 2) % 3;   // this wave's own region of that
                                                // buffer was consumed at cix-1
                gld16(gbaseA + (cix + 2) * CHD, (void*)(tbuf4 + nb * 2048 + wave * 128));
                gld16(gbaseB + (cix + 2) * CHD, (void*)(tbuf4 + nb * 2048 + wave * 128 + 64));
            }
            // ---- consume chunk cix: advance the 4 row chains over 32 dims
            {
                const float4* tb = tbuf4 + (cix % 3) * 2048 + (tok << 3);
                const float4* cr = cent4 + (g * 4) * CSTR + (cix << 3);
#pragma unroll
                for (int j4 = 0; j4 < CF4; ++j4) {
                    float4 a  = tb[j4 ^ s7];            // 8 distinct quads / phase
                    float4 c0 = cr[j4];                 // phase-uniform broadcasts
                    float4 c1 = cr[CSTR + j4];
                    float4 c2 = cr[2 * CSTR + j4];
                    float4 c3 = cr[3 * CSTR + j4];
                    acc[0] = dot4chain(a, c0, acc[0]);
                    acc[1] = dot4chain(a, c1, acc[1]);
                    acc[2] = dot4chain(a, c2, acc[2]);
                    acc[3] = dot4chain(a, c3, acc[3]);
                }
            }
        }

        // ---- masks: thread (tok,g) writes float {0,1} for clusters (2g, 2g+1)
        {
            float2 mf;
            mf.x = (acc[1] > acc[0]) ? 1.f : 0.f;    // cluster 2g   (ties -> 0)
            mf.y = (acc[3] > acc[2]) ? 1.f : 0.f;    // cluster 2g+1
            *(float2*)(maskFf + tok * KC + 2 * g) = mf;
        }
        __syncthreads();   // masks visible to all; all waves past sim sweep

        if (it == ITERS - 1 && t < NT) {
            float4* op = (float4*)(out_assign + ((size_t)b * NT + t) * KC);
            op[0] = maskF4[2 * t]; op[1] = maskF4[2 * t + 1];
        }

        // ==== accumulate (R3 form): thread t<768 owns dim d=t, all 8 clusters;
        // ==== writes BOTH unnormalized centroid rows (c1 = a_k, c0 = tsum - a_k)
        if (t < DD) {
            const int d = t;
            const float* col = tpb + d;
            float a0 = 0.f, a1 = 0.f, a2 = 0.f, a3 = 0.f;
            float a4 = 0.f, a5 = 0.f, a6 = 0.f, a7 = 0.f;
            float tr = 0.f;
            for (int n0 = 0; n0 < NT; n0 += 16) {
                float v[16];
#pragma unroll
                for (int u = 0; u < 16; ++u)
                    v[u] = col[(size_t)(n0 + u) * DD];          // coalesced 256B/wave
#pragma unroll
                for (int u = 0; u < 16; ++u) {
                    float4 ma = maskF4[2 * (n0 + u)];           // wave-uniform broadcast
                    float4 mb = maskF4[2 * (n0 + u) + 1];
                    a0 = fmaf(v[u], ma.x, a0);
                    a1 = fmaf(v[u], ma.y, a1);
                    a2 = fmaf(v[u], ma.z, a2);
                    a3 = fmaf(v[u], ma.w, a3);
                    a4 = fmaf(v[u], mb.x, a4);
                    a5 = fmaf(v[u], mb.y, a5);
                    a6 = fmaf(v[u], mb.z, a6);
                    a7 = fmaf(v[u], mb.w, a7);
                    if (it == 0) tr += v[u];                    // n-ascending chain
                }
            }
            if (it == 0) tsum_reg = tr;
            // rows r=2k+1 get a_k; rows r=2k get tsum-a_k (same subtraction the
            // normalize path originally performed -> identical values)
            centf[ 1 * 772 + d] = a0;  centf[ 0 * 772 + d] = tsum_reg - a0;
            centf[ 3 * 772 + d] = a1;  centf[ 2 * 772 + d] = tsum_reg - a1;
            centf[ 5 * 772 + d] = a2;  centf[ 4 * 772 + d] = tsum_reg - a2;
            centf[ 7 * 772 + d] = a3;  centf[ 6 * 772 + d] = tsum_reg - a3;
            centf[ 9 * 772 + d] = a4;  centf[ 8 * 772 + d] = tsum_reg - a4;
            centf[11 * 772 + d] = a5;  centf[10 * 772 + d] = tsum_reg - a5;
            centf[13 * 772 + d] = a6;  centf[12 * 772 + d] = tsum_reg - a6;
            centf[15 * 772 + d] = a7;  centf[14 * 772 + d] = tsum_reg - a7;
        }
        __syncthreads();

        // ==== normalize in place: wave r reads its centf row, reduces, scales
        {
            const int r = wave;
            float vals[12];
            float ss = 0.f;
#pragma unroll
            for (int j = 0; j < 12; ++j) {
                vals[j] = centf[r * 772 + lane + 64 * j];
                ss = fmaf(vals[j], vals[j], ss);
            }
            ss = waveReduceSum(ss);
            float iv = 1.0f / fmaxf(sqrtf(ss), 1e-12f);
#pragma unroll
            for (int j = 0; j < 12; ++j)
                centf[r * 772 + lane + 64 * j] = vals[j] * iv;
        }
        __syncthreads();   // cent ready; tbuf is wave-private, next iter may stage
    }

    // ---- scatter: vc[idx,0,0] += centroids_final[b,k,0,0] (c0 row, element 0)
    if (t < KC) {
        atomicAdd(delta + sidx[t], centf[(2 * t) * 772]);
    }
}

__global__ __launch_bounds__(1024) void vcnorm_kernel(
    const float* __restrict__ vc,
    const float* __restrict__ delta,
    float* __restrict__ out)          // (V, 2, D)
{
    const int t = threadIdx.x;
    const int lane = t & 63;
    const int wave = t >> 6;
    const int r = blockIdx.x * 16 + wave;     // row in [0, 2V)
    if (r >= 2 * VV) return;
    const int v = r >> 1;
    const int c = r & 1;
    const float* src = vc + (size_t)r * DD;
    float4 x[3];
#pragma unroll
    for (int j = 0; j < 3; ++j)
        x[j] = *(const float4*)(src + (lane + 64 * j) * 4);
    if (c == 0 && lane == 0) x[0].x += delta[v];
    float ss = 0.f;
#pragma unroll
    for (int j = 0; j < 3; ++j)
        ss += x[j].x * x[j].x + x[j].y * x[j].y + x[j].z * x[j].z + x[j].w * x[j].w;
    ss = waveReduceSum(ss);
    float iv = 1.0f / fmaxf(sqrtf(ss), 1e-12f);
    float* dst = out + (size_t)r * DD;
#pragma unroll
    for (int j = 0; j < 3; ++j) {
        float4 y = make_float4(x[j].x * iv, x[j].y * iv, x[j].z * iv, x[j].w * iv);
        *(float4*)(dst + (lane + 64 * j) * 4) = y;
    }
}

extern "C" void kernel_launch(void* const* d_in, const int* in_sizes, int n_in,
                              void* d_out, int out_size, void* d_ws, size_t ws_size,
                              hipStream_t stream) {
    const float* tokens = (const float*)d_in[0];
    const float* vc     = (const float*)d_in[1];
    const int*   topk   = (const int*)d_in[2];
    float* out          = (float*)d_out;
    float* assignments  = out;                                   // B*NT*KC floats
    float* vcnew        = out + (size_t)BB * NT * KC;            // V*2*D floats
    float* delta        = (float*)d_ws;                          // V floats

    hipMemsetAsync(delta, 0, VV * sizeof(float), stream);
    hipLaunchKernelGGL(kmeans_kernel, dim3(BB), dim3(1024), 0, stream,
                       tokens, vc, topk, assignments, delta);
    hipLaunchKernelGGL(vcnorm_kernel, dim3((2 * VV + 15) / 16), dim3(1024), 0, stream,
                       vc, delta, vcnew);
}